// Round 1
// baseline (523.643 us; speedup 1.0000x reference)
//
#include <hip/hip_runtime.h>

// ---------------------------------------------------------------------------
// StandAttention: out = softmax_causal((xWq+bq)(xWk+bk)^T / sqrt(d)) (xWv+bv) Wo + bo
// b=4, s=4096, d=1024. fp32 in/out, bf16 MFMA compute.
//
// R7 changes vs R6 (R6: 520 us; scores/proj dispatches at MfmaUtil 37%,
// VALUBusy 42% -> the 128^2/4-wave/2-barrier structural ceiling):
//  - NEW kernel gemm256 for the three uniform-K GEMMs (proj, scores, outproj):
//    256x256 tile, 8 waves (512 thr), BK=32, 4-slot LDS ring (128 KiB),
//    phase-split schedule: per K-tile 2 phases of {ds_read frags | stage 1
//    half of tile t+2 | s_barrier | 16 MFMA under setprio(1) | s_barrier},
//    counted s_waitcnt vmcnt(4) once per K-tile (never 0 in steady state).
//    Race-free by construction: slot written at block t was last read at
//    block t-2 (ds_reads complete before that block's final barrier); vmcnt(4)
//    at end of block t guarantees tile t+1 resident before its reads.
//  - PV (MODE 2, variable-K causal) kept on the old 128^2 kernel this round.
// ---------------------------------------------------------------------------

typedef unsigned short u16;
typedef __attribute__((ext_vector_type(4))) unsigned short u16x4;
typedef __attribute__((ext_vector_type(8))) unsigned short u16x8;
typedef __attribute__((ext_vector_type(8))) __bf16 bf16x8;
typedef __attribute__((ext_vector_type(4))) float f32x4;

typedef const __attribute__((address_space(1))) void* as1cp;
typedef __attribute__((address_space(3))) void* as3p;

struct GemmPtrs {
  const u16* A[4];
  const u16* B[4];
  const float* bias[4];
  void* C[4];
};
struct TransPtrs {
  const void* in[4];
  u16* out[4];
};
struct SmPtrs {
  u16* P[4];
};

__device__ __forceinline__ u16 f2bf(float f) {
  union { float f; unsigned int i; } c; c.f = f;
  unsigned int r = c.i + 0x7fffu + ((c.i >> 16) & 1u);   // RNE
  return (u16)(r >> 16);
}
__device__ __forceinline__ float bf2f(u16 u) {
  union { unsigned int i; float f; } c; c.i = ((unsigned int)u) << 16;
  return c.f;
}

// ---------------- cast fp32 -> bf16 (vectorized) ----------------
__global__ __launch_bounds__(256) void cast_f32_bf16(const float* __restrict__ in,
                                                     u16* __restrict__ out, int n4) {
  int i = blockIdx.x * blockDim.x + threadIdx.x;
  if (i >= n4) return;
  float4 v = ((const float4*)in)[i];
  u16x4 u;
  u.x = f2bf(v.x); u.y = f2bf(v.y); u.z = f2bf(v.z); u.w = f2bf(v.w);
  ((u16x4*)out)[i] = u;
}

// ---------------- LDS-tiled transpose (-> bf16), batched by z ----------------
template <bool IN_F32>
__global__ __launch_bounds__(256) void transpose_to_bf16(TransPtrs tp, int R, int C) {
  __shared__ u16 t[32][34];
  int z = blockIdx.z;
  int tx = threadIdx.x, ty = threadIdx.y;
  int c0 = blockIdx.x * 32, r0 = blockIdx.y * 32;
#pragma unroll
  for (int dy = 0; dy < 4; ++dy) {
    int r = r0 + ty + dy * 8;
    int c = c0 + tx;
    u16 hv;
    if (IN_F32) hv = f2bf(((const float*)tp.in[z])[(size_t)r * C + c]);
    else        hv = ((const u16*)tp.in[z])[(size_t)r * C + c];
    t[ty + dy * 8][tx] = hv;
  }
  __syncthreads();
  u16* op = tp.out[z];
#pragma unroll
  for (int dy = 0; dy < 4; ++dy) {
    int a = ty + dy * 8;
    op[(size_t)(c0 + a) * R + r0 + tx] = t[tx][a];
  }
}

// ---------------- causal softmax, in-place, trimmed to j<=row ----------------
__global__ __launch_bounds__(256) void softmax_causal(SmPtrs sp) {
  int row = blockIdx.x;
  u16* P = sp.P[blockIdx.y];
  int tid = threadIdx.x;
  int lane = tid & 63, wv = tid >> 6;
  u16x8* prow = (u16x8*)(P + (size_t)row * 4096);
  int nch = (row >> 3) + 1;           // vec8 chunks containing any j<=row
  int fend = ((row >> 7) + 1) << 4;   // chunks to the 128 boundary PV reads
  int c0 = tid, c1 = tid + 256;
  bool a0 = c0 < nch, a1 = c1 < nch;
  float vals[16];
  float lmax = -3.0e38f;
  if (a0) {
    u16x8 u = prow[c0];
#pragma unroll
    for (int e = 0; e < 8; ++e) {
      float f = (c0 * 8 + e <= row) ? bf2f(u[e]) : -3.0e38f;
      vals[e] = f; lmax = fmaxf(lmax, f);
    }
  } else {
#pragma unroll
    for (int e = 0; e < 8; ++e) vals[e] = -3.0e38f;
  }
  if (a1) {
    u16x8 u = prow[c1];
#pragma unroll
    for (int e = 0; e < 8; ++e) {
      float f = (c1 * 8 + e <= row) ? bf2f(u[e]) : -3.0e38f;
      vals[8 + e] = f; lmax = fmaxf(lmax, f);
    }
  } else {
#pragma unroll
    for (int e = 0; e < 8; ++e) vals[8 + e] = -3.0e38f;
  }
  __shared__ float red[8];
#pragma unroll
  for (int off = 32; off > 0; off >>= 1) lmax = fmaxf(lmax, __shfl_down(lmax, off, 64));
  if (lane == 0) red[wv] = lmax;
  __syncthreads();
  float m2 = fmaxf(fmaxf(red[0], red[1]), fmaxf(red[2], red[3]));
  float lsum = 0.f;
#pragma unroll
  for (int e = 0; e < 16; ++e) {
    float ev = __expf(vals[e] - m2);
    vals[e] = ev;
    lsum += ev;
  }
#pragma unroll
  for (int off = 32; off > 0; off >>= 1) lsum += __shfl_down(lsum, off, 64);
  if (lane == 0) red[4 + wv] = lsum;
  __syncthreads();
  float inv = 1.0f / (red[4] + red[5] + red[6] + red[7]);
  if (a0) {
    u16x8 u;
#pragma unroll
    for (int e = 0; e < 8; ++e) u[e] = f2bf(vals[e] * inv);
    prow[c0] = u;
  }
  if (a1) {
    u16x8 u;
#pragma unroll
    for (int e = 0; e < 8; ++e) u[e] = f2bf(vals[8 + e] * inv);
    prow[c1] = u;
  }
  u16x8 zz = (u16x8)(u16)0;
  for (int c = nch + tid; c < fend; c += 256) prow[c] = zz;
}

// ---------------------------------------------------------------------------
// gemm256: 256x256-tile phase-split GEMM. C[M,N] = A[M,K=1024] @ Bt[N,K=1024]^T
// 8 waves (2M x 4N), per-wave output 128x64. BK=32 -> 32 K-tiles, 4-slot LDS
// ring. Per K-tile: 2 phases x 16 MFMA; stage tile t+2 (A-half in phase 0,
// B-half in phase 1); vmcnt(4) at end of each K-tile.
// MODE 0: q/k/v proj (3 slots, z=s)  MODE 1: causal scores (2|3 slots)
// MODE 3: out-projection (1 slot)
// ---------------------------------------------------------------------------
template <int MODE, bool OUT_BF16, bool HAS_BIAS>
__global__ __launch_bounds__(512, 2) void gemm256(GemmPtrs p, int N, float cscale) {
  __shared__ __align__(16) u16 As[4][8192];   // 4 slots x 256 rows x 32 k
  __shared__ __align__(16) u16 Bs[4][8192];
  const int b = blockIdx.x;
  const int tid = threadIdx.x, lane = tid & 63, wv = tid >> 6;
  const int wm = (wv >> 2) << 7, wn = (wv & 3) << 6;
  const int lrow = lane & 15, lquad = lane >> 4;
  // read-side XOR swizzle: elem = r*32 + ((lquad ^ ((r>>1)&3))<<3); with
  // r = base+lrow the xor term reduces to lane-only. Conflict-free at 8-lane
  // b128 granularity (lanes 0-7 cover all 32 banks).
  const int xs = (lquad ^ ((lrow >> 1) & 3)) << 3;
  const int aoff0 = (wm + lrow) * 32 + xs;
  const int boff0 = (wn + lrow) * 32 + xs;
  // stage source offset: dest is linear (global_load_lds), so the source
  // column chunk is pre-swizzled: row = tid>>2 (+128 for hi half),
  // chunk = (tid&3) ^ ((tid>>3)&3).
  const int soff = (tid >> 2) * 1024 + (((tid & 3) ^ ((tid >> 3) & 3)) << 3);
  const int nslot = (MODE == 1) ? (b < 32 ? 3 : 2) : (MODE == 0 ? 3 : 1);

  struct TP { const u16* A; const u16* B; int tm, tn, z; };
  auto tileOf = [&](int s) {
    TP t;
    if (MODE == 0) {
      int g = s * 256 + b;                 // g>>8 == s == matrix index
      t.z = g >> 8; int i = g & 255;
      t.tm = (i >> 2) << 8; t.tn = (i & 3) << 8;
    } else if (MODE == 1) {
      int g = s * 256 + b;                 // 544 lower-tri tiles total
      t.z = g / 136; int L = g - t.z * 136;
      int i = (int)((__fsqrt_rn(8.f * (float)L + 1.f) - 1.f) * 0.5f);
      while ((i + 1) * (i + 2) / 2 <= L) ++i;
      while (i * (i + 1) / 2 > L) --i;
      t.tm = i << 8; t.tn = (L - ((i * (i + 1)) >> 1)) << 8;
    } else {
      t.z = 0; t.tm = (b >> 2) << 8; t.tn = (b & 3) << 8;
    }
    t.A = p.A[t.z] + (size_t)t.tm * 1024;
    t.B = p.B[t.z] + (size_t)t.tn * 1024;
    return t;
  };

  auto stageA = [&](int slot, const u16* src) __attribute__((always_inline)) {
    __builtin_amdgcn_global_load_lds((as1cp)src, (as3p)&As[slot][wv * 512], 16, 0, 0);
    __builtin_amdgcn_global_load_lds((as1cp)(src + 131072),
                                     (as3p)&As[slot][4096 + wv * 512], 16, 0, 0);
  };
  auto stageB = [&](int slot, const u16* src) __attribute__((always_inline)) {
    __builtin_amdgcn_global_load_lds((as1cp)src, (as3p)&Bs[slot][wv * 512], 16, 0, 0);
    __builtin_amdgcn_global_load_lds((as1cp)(src + 131072),
                                     (as3p)&Bs[slot][4096 + wv * 512], 16, 0, 0);
  };

  f32x4 acc[8][4];

  // One K-tile (= 2 phases). tu = slot of the tile being computed (t & 3).
  // stg: stage tile t+2 into slot (tu+2)&3. vm: 4 normal, 0 tail-drain, -1 none.
  auto doBlock = [&](int tu, bool stg, const u16* sA, const u16* sB, int vm)
      __attribute__((always_inline)) {
    const int sT = (tu + 2) & 3;
    bf16x8 af[4], bg[4];
#pragma unroll
    for (int m = 0; m < 4; ++m) af[m] = *(const bf16x8*)&As[tu][aoff0 + m * 512];
#pragma unroll
    for (int n = 0; n < 4; ++n) bg[n] = *(const bf16x8*)&Bs[tu][boff0 + n * 512];
    if (stg) stageA(sT, sA);
    asm volatile("s_barrier" ::: "memory");
    __builtin_amdgcn_s_setprio(1);
#pragma unroll
    for (int m = 0; m < 4; ++m)
#pragma unroll
      for (int n = 0; n < 4; ++n)
        acc[m][n] = __builtin_amdgcn_mfma_f32_16x16x32_bf16(af[m], bg[n], acc[m][n], 0, 0, 0);
    __builtin_amdgcn_s_setprio(0);
    asm volatile("s_barrier" ::: "memory");
    // phase 1: upper 4 M-frags, B held in registers
#pragma unroll
    for (int m = 0; m < 4; ++m) af[m] = *(const bf16x8*)&As[tu][aoff0 + 2048 + m * 512];
    if (stg) stageB(sT, sB);
    asm volatile("s_barrier" ::: "memory");
    __builtin_amdgcn_s_setprio(1);
#pragma unroll
    for (int m = 0; m < 4; ++m)
#pragma unroll
      for (int n = 0; n < 4; ++n)
        acc[4 + m][n] = __builtin_amdgcn_mfma_f32_16x16x32_bf16(af[m], bg[n], acc[4 + m][n], 0, 0, 0);
    __builtin_amdgcn_s_setprio(0);
    if (vm == 4)      asm volatile("s_waitcnt vmcnt(4)" ::: "memory");
    else if (vm == 0) asm volatile("s_waitcnt vmcnt(0)" ::: "memory");
    asm volatile("s_barrier" ::: "memory");
  };

  TP ct = tileOf(0);
  const u16* gA = ct.A + soff;
  const u16* gB = ct.B + soff;
  // prologue: tiles 0,1 -> slots 0,1; wait tile 0 (leave tile 1's 4 in flight)
  stageA(0, gA); stageB(0, gB);
  stageA(1, gA + 32); stageB(1, gB + 32);
  asm volatile("s_waitcnt vmcnt(4)" ::: "memory");
  asm volatile("s_barrier" ::: "memory");

  for (int s = 0;;) {
#pragma unroll
    for (int i = 0; i < 8; ++i)
#pragma unroll
      for (int j = 0; j < 4; ++j) acc[i][j] = (f32x4){0.f, 0.f, 0.f, 0.f};

    for (int u = 0; u < 7; ++u) {
#pragma unroll
      for (int tu = 0; tu < 4; ++tu)
        doBlock(tu, true, gA + (tu + 2) * 32, gB + (tu + 2) * 32, 4);
      gA += 128; gB += 128;
    }
    // tail: t = 28..31 (gA at +896; tiles 30,31 at +960,+992)
    doBlock(0, true, gA + 64, gB + 64, 4);
    doBlock(1, true, gA + 96, gB + 96, 4);
    doBlock(2, false, nullptr, nullptr, 0);
    doBlock(3, false, nullptr, nullptr, -1);

    bool more = (++s < nslot);
    TP nt2;
    if (more) {
      nt2 = tileOf(s);
      gA = nt2.A + soff; gB = nt2.B + soff;
      stageA(0, gA); stageB(0, gB);        // hide next-slot tile0 under epilogue
    }
    {  // epilogue for ct
      float bvv[4] = {0.f, 0.f, 0.f, 0.f};
      if (HAS_BIAS) {
        const float* bias = p.bias[ct.z];
#pragma unroll
        for (int n = 0; n < 4; ++n) bvv[n] = bias[ct.tn + wn + n * 16 + lrow];
      }
#pragma unroll
      for (int m = 0; m < 8; ++m)
#pragma unroll
        for (int r = 0; r < 4; ++r) {
          size_t row = (size_t)(ct.tm + wm + m * 16 + lquad * 4 + r);
#pragma unroll
          for (int n = 0; n < 4; ++n) {
            int col = ct.tn + wn + n * 16 + lrow;
            float vvv = acc[m][n][r] * cscale + bvv[n];
            if (OUT_BF16) ((u16*)p.C[ct.z])[row * N + col] = f2bf(vvv);
            else          ((float*)p.C[ct.z])[row * N + col] = vvv;
          }
        }
    }
    if (!more) return;
    stageA(1, gA + 32); stageB(1, gB + 32);
    asm volatile("s_waitcnt vmcnt(4)" ::: "memory");  // stores + tile0 drained
    asm volatile("s_barrier" ::: "memory");
    ct = nt2;
  }
}

// ---------------- persistent MFMA GEMM (kept for MODE 2 / PV) ----------------
template <int MODE, bool OUT_BF16, bool HAS_BIAS, int MAXSLOT, int KDIM, int LDB>
__global__ __launch_bounds__(256) void gemm_persist(GemmPtrs p, int N, float cscale) {
  __shared__ __align__(16) u16 As[2][128 * 64];
  __shared__ __align__(16) u16 Bs[2][128 * 64];
  int b = blockIdx.x;
  int x = b & 7, q = b >> 3;                  // x = XCD, q = index on XCD
  int tid = threadIdx.x, lane = tid & 63, wv = tid >> 6;
  int wm = (wv >> 1) * 64, wn = (wv & 1) * 64;
  int lrow = lane & 15, lquad = lane >> 4;
  int srow = lane >> 3, scol = ((lane & 7) ^ srow) * 8;

  struct TP { const u16* A; const u16* B; int niter, tm, tn, z; };
  auto tileOf = [&](int s) {
    TP t;
    if (MODE == 0) {
      int c = x + 8 * (s * 8 + (q >> 3));
      t.z = c >> 7;
      t.tm = (c & 127) << 7; t.tn = (q & 7) << 7; t.niter = KDIM >> 6;
    } else if (MODE == 1) {
      int c = x + 8 * (s * 8 + (q >> 3));
      int tt = c * 8 + (q & 7);
      t.z = tt / 528; int L = tt - t.z * 528;
      int i = (int)((__fsqrt_rn(8.f * (float)L + 1.f) - 1.f) * 0.5f);
      while ((i + 1) * (i + 2) / 2 <= L) ++i;
      while (i * (i + 1) / 2 > L) --i;
      t.tm = i << 7; t.tn = (L - ((i * (i + 1)) >> 1)) << 7; t.niter = KDIM >> 6;
    } else if (MODE == 2) {
      int w = q & 15, h = w >> 3;
      int i = (s == 0) ? (h ? 15 - x : x) : (h ? 16 + x : 31 - x);
      t.z = q >> 4; t.tm = i << 7; t.tn = (w & 7) << 7; t.niter = (i + 1) * 2;
    } else {
      int c = x + 8 * (s * 8 + (q >> 3));
      t.z = 0; t.tm = c << 7; t.tn = (q & 7) << 7; t.niter = KDIM >> 6;
    }
    t.A = p.A[t.z] + (size_t)t.tm * KDIM;
    t.B = p.B[t.z] + (size_t)t.tn * LDB;
    return t;
  };
  int nslot = (MODE == 1) ? ((q >> 3) == 0 ? 5 : 4) : MAXSLOT;
  int total = (MODE == 2) ? 66 : nslot * (KDIM >> 6);

  int aoff = (wv * 32 + srow) * KDIM + scol;
  int boff = (wv * 32 + srow) * LDB + scol;

  TP st = tileOf(0);
  int stk = 0, sslot = 0;
  const u16* gA = st.A + aoff;
  const u16* gB = st.B + boff;

  auto stageTo = [&](int sb) {
#pragma unroll
    for (int tt = 0; tt < 4; ++tt) {
      __builtin_amdgcn_global_load_lds((as1cp)(gA + tt * 8 * KDIM),
                                       (as3p)&As[sb][(wv * 4 + tt) * 512], 16, 0, 0);
      __builtin_amdgcn_global_load_lds((as1cp)(gB + tt * 8 * LDB),
                                       (as3p)&Bs[sb][(wv * 4 + tt) * 512], 16, 0, 0);
    }
  };
  auto adv = [&]() {
    gA += 64; gB += 64;
    if (++stk == st.niter) {
      stk = 0;
      if (++sslot < nslot) {
        st = tileOf(sslot);
        gA = st.A + aoff;
        gB = st.B + boff;
      }
    }
  };

  f32x4 acc[4][4];
#pragma unroll
  for (int i = 0; i < 4; ++i)
#pragma unroll
    for (int j = 0; j < 4; ++j) acc[i][j] = (f32x4){0.f, 0.f, 0.f, 0.f};

  auto compute = [&](int cb) __attribute__((always_inline)) {
#pragma unroll
    for (int ks = 0; ks < 64; ks += 32) {
      bf16x8 af[4], bg[4];
#pragma unroll
      for (int mt = 0; mt < 4; ++mt) {
        int r = wm + mt * 16 + lrow;
        int jb = (ks >> 3) + lquad;
        af[mt] = *(const bf16x8*)&As[cb][r * 64 + ((jb ^ (r & 7)) << 3)];
      }
#pragma unroll
      for (int nt = 0; nt < 4; ++nt) {
        int r = wn + nt * 16 + lrow;
        int jb = (ks >> 3) + lquad;
        bg[nt] = *(const bf16x8*)&Bs[cb][r * 64 + ((jb ^ (r & 7)) << 3)];
      }
#pragma unroll
      for (int mt = 0; mt < 4; ++mt)
#pragma unroll
        for (int nt = 0; nt < 4; ++nt)
          acc[mt][nt] = __builtin_amdgcn_mfma_f32_16x16x32_bf16(af[mt], bg[nt], acc[mt][nt], 0, 0, 0);
    }
  };

  TP ct = st;
  int cit = 0, cslot = 0;
  auto epi = [&]() {
    if (++cit == ct.niter) {
      const float* bias = HAS_BIAS ? p.bias[ct.z] : nullptr;
#pragma unroll
      for (int mt = 0; mt < 4; ++mt) {
#pragma unroll
        for (int reg = 0; reg < 4; ++reg) {
          int r = ct.tm + wm + mt * 16 + lquad * 4 + reg;
#pragma unroll
          for (int nt = 0; nt < 4; ++nt) {
            int cidx = ct.tn + wn + nt * 16 + lrow;
            float vvv = acc[mt][nt][reg] * cscale;
            if (HAS_BIAS) vvv += bias[cidx];
            if (OUT_BF16) ((u16*)p.C[ct.z])[(size_t)r * N + cidx] = f2bf(vvv);
            else          ((float*)p.C[ct.z])[(size_t)r * N + cidx] = vvv;
          }
        }
      }
#pragma unroll
      for (int i = 0; i < 4; ++i)
#pragma unroll
        for (int j = 0; j < 4; ++j) acc[i][j] = (f32x4){0.f, 0.f, 0.f, 0.f};
      cit = 0;
      if (++cslot < nslot) ct = tileOf(cslot);
    }
  };

  stageTo(0);
  adv();
  for (int it = 0; it < total; it += 2) {
    if (it + 1 < total) {
      stageTo(1);
      adv();
      asm volatile("s_waitcnt vmcnt(8)" ::: "memory");
    } else {
      asm volatile("s_waitcnt vmcnt(0)" ::: "memory");
    }
    asm volatile("s_barrier" ::: "memory");
    compute(0);
    asm volatile("s_barrier" ::: "memory");
    epi();
    if (it + 2 < total) {
      stageTo(0);
      adv();
      asm volatile("s_waitcnt vmcnt(8)" ::: "memory");
    } else {
      asm volatile("s_waitcnt vmcnt(0)" ::: "memory");
    }
    asm volatile("s_barrier" ::: "memory");
    compute(1);
    asm volatile("s_barrier" ::: "memory");
    epi();
  }
}

// ---------------------------------------------------------------------------
extern "C" void kernel_launch(void* const* d_in, const int* in_sizes, int n_in,
                              void* d_out, int out_size, void* d_ws, size_t ws_size,
                              hipStream_t stream) {
  const float* x  = (const float*)d_in[0];
  const float* Wq = (const float*)d_in[1];
  const float* bq = (const float*)d_in[2];
  const float* Wk = (const float*)d_in[3];
  const float* bk = (const float*)d_in[4];
  const float* Wv = (const float*)d_in[5];
  const float* bv = (const float*)d_in[6];
  const float* Wo = (const float*)d_in[7];
  const float* bo = (const float*)d_in[8];

  const int S = 4096, D = 1024;
  const size_t XE = (size_t)4 * S * D;
  const size_t BSE = (size_t)S * D;

  char* ws = (char*)d_ws;
  u16* xb  = (u16*)(ws + 0);                     // [16384,1024]; dead after proj -> vT
  u16* q   = (u16*)(ws + 33554432);
  u16* k   = (u16*)(ws + 67108864);
  u16* v   = (u16*)(ws + 100663296);             // dead after transpose -> attn3
  u16* ctx = (u16*)(ws + 134217728);
  u16* wqT = (u16*)(ws + 167772160);
  u16* wkT = wqT + 1048576;
  u16* wvT = wkT + 1048576;
  u16* woT = wvT + 1048576;
  u16* attn2 = (u16*)(ws + 176160768);           // [4096,4096] bf16
  u16* attn0 = (u16*)d_out;                      // d_out 67MB, dead until out-proj
  u16* attn1 = attn0 + (size_t)S * S;
  u16* attn3 = v;
  u16* vT = xb;                                  // [1024,4096] per batch, contiguous
  u16* attn[4] = {attn0, attn1, attn2, attn3};

  // 1. cast x -> bf16
  cast_f32_bf16<<<(int)(XE / 4 / 256), 256, 0, stream>>>(x, xb, (int)(XE / 4));
  // 2. weight transposes
  {
    TransPtrs tp = {{Wq, Wk, Wv, Wo}, {wqT, wkT, wvT, woT}};
    transpose_to_bf16<true><<<dim3(32, 32, 4), dim3(32, 8), 0, stream>>>(tp, D, D);
  }
  // 3. q/k/v projections: 768 256x256 tiles over 256 blocks (3 slots)
  {
    GemmPtrs gp = {{xb, xb, xb, xb}, {wqT, wkT, wvT, wqT},
                   {bq, bk, bv, bq}, {q, k, v, q}};
    gemm256<0, true, true><<<256, 512, 0, stream>>>(gp, D, 1.0f);
  }
  // 4. v -> v^T per batch (overwrites dead xb)
  {
    TransPtrs tp = {{v, v + BSE, v + 2 * BSE, v + 3 * BSE},
                    {vT, vT + BSE, vT + 2 * BSE, vT + 3 * BSE}};
    transpose_to_bf16<false><<<dim3(D / 32, S / 32, 4), dim3(32, 8), 0, stream>>>(tp, S, D);
  }
  // 5. scores = (q k^T)*scale -> bf16 attn_z: 544 lower-tri 256-tiles over 256 blocks
  {
    GemmPtrs gp = {{q, q + BSE, q + 2 * BSE, q + 3 * BSE},
                   {k, k + BSE, k + 2 * BSE, k + 3 * BSE},
                   {nullptr, nullptr, nullptr, nullptr},
                   {attn[0], attn[1], attn[2], attn[3]}};
    gemm256<1, true, false><<<256, 512, 0, stream>>>(gp, S, 0.03125f);
  }
  // 6. causal softmax in-place (trimmed + fringe zeros)
  {
    SmPtrs sp = {{attn[0], attn[1], attn[2], attn[3]}};
    softmax_causal<<<dim3(S, 4), 256, 0, stream>>>(sp);
  }
  // 7. ctx = attn @ v (old 128^2 kernel; XCD-local i-sets, 33 iters per block)
  {
    GemmPtrs gp = {{attn[0], attn[1], attn[2], attn[3]},
                   {vT, vT + BSE, vT + 2 * BSE, vT + 3 * BSE},
                   {nullptr, nullptr, nullptr, nullptr},
                   {ctx, ctx + BSE, ctx + 2 * BSE, ctx + 3 * BSE}};
    gemm_persist<2, true, false, 2, 4096, 4096><<<512, 256, 0, stream>>>(gp, D, 1.0f);
  }
  // 8. out = ctx Wo^T + bo: 256 tiles, 1 slot
  {
    GemmPtrs gp = {{ctx, ctx, ctx, ctx}, {woT, woT, woT, woT},
                   {bo, bo, bo, bo}, {d_out, d_out, d_out, d_out}};
    gemm256<3, false, true><<<256, 512, 0, stream>>>(gp, D, 1.0f);
  }
}

// Round 2
// 522.382 us; speedup vs baseline: 1.0024x; 1.0024x over previous
//
#include <hip/hip_runtime.h>

// ---------------------------------------------------------------------------
// StandAttention: out = softmax_causal((xWq+bq)(xWk+bk)^T / sqrt(d)) (xWv+bv) Wo + bo
// b=4, s=4096, d=1024. fp32 in/out, bf16 MFMA compute.
//
// R8 changes vs R7 (R7: 523 us; gemm256 MfmaUtil stuck at 36%, VALUBusy 18 ->
// ds_read time serializes with MFMA because reads sit between the two barriers
// where no wave computes; ~2900cyc/K-tile vs 1240 MFMA content):
//  - gemm256p: register-level software pipeline. Per phase: {MFMA using frags
//    read LAST phase | ds_read next phase's frags (overlaps co-wave MFMA) |
//    stage | [vmcnt(6) once per K-tile] | ONE s_barrier}. 4-slot LDS ring,
//    stage distance 3. Publication: vmcnt is in-order; newest-6 at the wait
//    point = tiles g+2,g+3a, so vmcnt(6)+barrier publishes g+1 for the reads
//    issued next phase. 2 barriers/K-tile (was 4), reads hidden under MFMA.
//  - PV ported to same schedule (gemm_pv): 128x256 tiles, pair (i,31-i) ->
//    exactly 132 K-tiles per block, 256 blocks, perfectly balanced (old PV
//    was 122us at 37% util). Single-phase K-tiles, vmcnt(3), 96 KiB LDS.
//  - XCD-clustered tile maps restored (R7 lost them; FETCH 93->210MB):
//    scores: per-XCD contiguous 68-tile tri ranges; proj/outproj: 8-row bands.
// ---------------------------------------------------------------------------

typedef unsigned short u16;
typedef __attribute__((ext_vector_type(4))) unsigned short u16x4;
typedef __attribute__((ext_vector_type(8))) unsigned short u16x8;
typedef __attribute__((ext_vector_type(8))) __bf16 bf16x8;
typedef __attribute__((ext_vector_type(4))) float f32x4;

typedef const __attribute__((address_space(1))) void* as1cp;
typedef __attribute__((address_space(3))) void* as3p;

template <int N> struct IC { static constexpr int v = N; };

struct GemmPtrs {
  const u16* A[4];
  const u16* B[4];
  const float* bias[4];
  void* C[4];
};
struct TransPtrs {
  const void* in[4];
  u16* out[4];
};
struct SmPtrs {
  u16* P[4];
};

__device__ __forceinline__ u16 f2bf(float f) {
  union { float f; unsigned int i; } c; c.f = f;
  unsigned int r = c.i + 0x7fffu + ((c.i >> 16) & 1u);   // RNE
  return (u16)(r >> 16);
}
__device__ __forceinline__ float bf2f(u16 u) {
  union { unsigned int i; float f; } c; c.i = ((unsigned int)u) << 16;
  return c.f;
}

// ---------------- cast fp32 -> bf16 (vectorized) ----------------
__global__ __launch_bounds__(256) void cast_f32_bf16(const float* __restrict__ in,
                                                     u16* __restrict__ out, int n4) {
  int i = blockIdx.x * blockDim.x + threadIdx.x;
  if (i >= n4) return;
  float4 v = ((const float4*)in)[i];
  u16x4 u;
  u.x = f2bf(v.x); u.y = f2bf(v.y); u.z = f2bf(v.z); u.w = f2bf(v.w);
  ((u16x4*)out)[i] = u;
}

// ---------------- LDS-tiled transpose (-> bf16), batched by z ----------------
template <bool IN_F32>
__global__ __launch_bounds__(256) void transpose_to_bf16(TransPtrs tp, int R, int C) {
  __shared__ u16 t[32][34];
  int z = blockIdx.z;
  int tx = threadIdx.x, ty = threadIdx.y;
  int c0 = blockIdx.x * 32, r0 = blockIdx.y * 32;
#pragma unroll
  for (int dy = 0; dy < 4; ++dy) {
    int r = r0 + ty + dy * 8;
    int c = c0 + tx;
    u16 hv;
    if (IN_F32) hv = f2bf(((const float*)tp.in[z])[(size_t)r * C + c]);
    else        hv = ((const u16*)tp.in[z])[(size_t)r * C + c];
    t[ty + dy * 8][tx] = hv;
  }
  __syncthreads();
  u16* op = tp.out[z];
#pragma unroll
  for (int dy = 0; dy < 4; ++dy) {
    int a = ty + dy * 8;
    op[(size_t)(c0 + a) * R + r0 + tx] = t[tx][a];
  }
}

// ---------------- causal softmax, in-place, trimmed to j<=row ----------------
__global__ __launch_bounds__(256) void softmax_causal(SmPtrs sp) {
  int row = blockIdx.x;
  u16* P = sp.P[blockIdx.y];
  int tid = threadIdx.x;
  int lane = tid & 63, wv = tid >> 6;
  u16x8* prow = (u16x8*)(P + (size_t)row * 4096);
  int nch = (row >> 3) + 1;           // vec8 chunks containing any j<=row
  int fend = ((row >> 7) + 1) << 4;   // chunks to the 128 boundary PV reads
  int c0 = tid, c1 = tid + 256;
  bool a0 = c0 < nch, a1 = c1 < nch;
  float vals[16];
  float lmax = -3.0e38f;
  if (a0) {
    u16x8 u = prow[c0];
#pragma unroll
    for (int e = 0; e < 8; ++e) {
      float f = (c0 * 8 + e <= row) ? bf2f(u[e]) : -3.0e38f;
      vals[e] = f; lmax = fmaxf(lmax, f);
    }
  } else {
#pragma unroll
    for (int e = 0; e < 8; ++e) vals[e] = -3.0e38f;
  }
  if (a1) {
    u16x8 u = prow[c1];
#pragma unroll
    for (int e = 0; e < 8; ++e) {
      float f = (c1 * 8 + e <= row) ? bf2f(u[e]) : -3.0e38f;
      vals[8 + e] = f; lmax = fmaxf(lmax, f);
    }
  } else {
#pragma unroll
    for (int e = 0; e < 8; ++e) vals[8 + e] = -3.0e38f;
  }
  __shared__ float red[8];
#pragma unroll
  for (int off = 32; off > 0; off >>= 1) lmax = fmaxf(lmax, __shfl_down(lmax, off, 64));
  if (lane == 0) red[wv] = lmax;
  __syncthreads();
  float m2 = fmaxf(fmaxf(red[0], red[1]), fmaxf(red[2], red[3]));
  float lsum = 0.f;
#pragma unroll
  for (int e = 0; e < 16; ++e) {
    float ev = __expf(vals[e] - m2);
    vals[e] = ev;
    lsum += ev;
  }
#pragma unroll
  for (int off = 32; off > 0; off >>= 1) lsum += __shfl_down(lsum, off, 64);
  if (lane == 0) red[4 + wv] = lsum;
  __syncthreads();
  float inv = 1.0f / (red[4] + red[5] + red[6] + red[7]);
  if (a0) {
    u16x8 u;
#pragma unroll
    for (int e = 0; e < 8; ++e) u[e] = f2bf(vals[e] * inv);
    prow[c0] = u;
  }
  if (a1) {
    u16x8 u;
#pragma unroll
    for (int e = 0; e < 8; ++e) u[e] = f2bf(vals[8 + e] * inv);
    prow[c1] = u;
  }
  u16x8 zz = (u16x8)(u16)0;
  for (int c = nch + tid; c < fend; c += 256) prow[c] = zz;
}

// ---------------------------------------------------------------------------
// gemm256p: 256x256-tile register-pipelined GEMM. C = A[M,1024] @ Bt[N,1024]^T
// 8 waves (2M x 4N), per-wave 128x64 out. BK=32, 4-slot LDS ring, stage
// distance 3, one barrier per phase, vmcnt(6) once per K-tile.
// MODE 0: q/k/v proj (3 slots, z=slot)  MODE 1: causal scores (3|2 slots)
// MODE 3: out-projection (1 slot)
// ---------------------------------------------------------------------------
template <int MODE, bool OUT_BF16, bool HAS_BIAS>
__global__ __launch_bounds__(512, 2) void gemm256p(GemmPtrs p, int N, float cscale) {
  __shared__ __align__(16) u16 As[4][8192];   // 4 slots x 256 rows x 32 k
  __shared__ __align__(16) u16 Bs[4][8192];
  const int b = blockIdx.x;
  const int tid = threadIdx.x, lane = tid & 63, wv = tid >> 6;
  const int wm = (wv >> 2) << 7, wn = (wv & 3) << 6;
  const int lrow = lane & 15, lquad = lane >> 4;
  const int xs = (lquad ^ ((lrow >> 1) & 3)) << 3;
  const int aoff0 = (wm + lrow) * 32 + xs;
  const int boff0 = (wn + lrow) * 32 + xs;
  // stage src pre-swizzle: LDS[r][c] = G[r][c ^ ((r>>1)&3)]
  const int soff = (tid >> 2) * 1024 + (((tid & 3) ^ ((tid >> 3) & 3)) << 3);
  const int x = b & 7, u = b >> 3;            // XCD, index-on-XCD
  const int nslot = (MODE == 1) ? (u < 4 ? 3 : 2) : (MODE == 0 ? 3 : 1);

  struct TP { const u16* A; const u16* B; int tm, tn, z; };
  auto tileOf = [&](int s) {
    TP t;
    if (MODE == 0) {
      int i = x * 32 + u;                 // 8-row band per XCD, reused over 3 mats
      t.z = s; t.tm = (i >> 2) << 8; t.tn = (i & 3) << 8;
    } else if (MODE == 1) {
      int g = x * 68 + s * 32 + u;        // per-XCD contiguous tri range
      t.z = g / 136; int L = g - t.z * 136;
      int i = (int)((__fsqrt_rn(8.f * (float)L + 1.f) - 1.f) * 0.5f);
      while ((i + 1) * (i + 2) / 2 <= L) ++i;
      while (i * (i + 1) / 2 > L) --i;
      t.tm = i << 8; t.tn = (L - ((i * (i + 1)) >> 1)) << 8;
    } else {
      int i = x * 32 + u;
      t.z = 0; t.tm = (i >> 2) << 8; t.tn = (i & 3) << 8;
    }
    t.A = p.A[t.z] + (size_t)t.tm * 1024;
    t.B = p.B[t.z] + (size_t)t.tn * 1024;
    return t;
  };

  // staging cursor (3 K-tiles ahead of compute)
  const u16* gA; const u16* gB; int stk = 0, sslot = 0;
  {
    TP t0 = tileOf(0);
    gA = t0.A + soff; gB = t0.B + soff;
  }
  auto adv = [&]() {
    gA += 32; gB += 32;
    ++stk;
    if (stk == 32 && sslot < nslot) {
      stk = 0; ++sslot;
      if (sslot < nslot) {
        TP t = tileOf(sslot);
        gA = t.A + soff; gB = t.B + soff;
      }
    }
  };

  f32x4 acc[8][4];
#pragma unroll
  for (int i = 0; i < 8; ++i)
#pragma unroll
    for (int j = 0; j < 4; ++j) acc[i][j] = (f32x4){0.f, 0.f, 0.f, 0.f};

  bf16x8 alo[4], ahi[4], bg0[4], bg1[4];

  // prologue: stage tiles 0,1,2 -> slots 0,1,2; publish tile 0; preload (0,0)
#pragma unroll
  for (int pt = 0; pt < 3; ++pt) {
    __builtin_amdgcn_global_load_lds((as1cp)gA, (as3p)(As[pt] + wv * 512), 16, 0, 0);
    __builtin_amdgcn_global_load_lds((as1cp)(gA + 131072), (as3p)(As[pt] + 4096 + wv * 512), 16, 0, 0);
    __builtin_amdgcn_global_load_lds((as1cp)gB, (as3p)(Bs[pt] + wv * 512), 16, 0, 0);
    __builtin_amdgcn_global_load_lds((as1cp)(gB + 131072), (as3p)(Bs[pt] + 4096 + wv * 512), 16, 0, 0);
    adv();
  }
  asm volatile("s_waitcnt vmcnt(8)" ::: "memory");
  asm volatile("s_barrier" ::: "memory");
#pragma unroll
  for (int m = 0; m < 4; ++m) alo[m] = *(const bf16x8*)&As[0][aoff0 + m * 512];
#pragma unroll
  for (int n = 0; n < 4; ++n) bg0[n] = *(const bf16x8*)&Bs[0][boff0 + n * 512];

  // one K-tile: ph0 {MFMA lo | read ahi | stageA(g+3) | vmcnt(6) | bar}
  //             ph1 {MFMA hi | read next alo+B | stageB(g+3)+adv | bar}
  auto kt = [&](auto CC, auto SS, auto VV, auto& BU, auto& BL)
      __attribute__((always_inline)) {
    constexpr int c = decltype(CC)::v;
    constexpr int stg = decltype(SS)::v;
    constexpr int vm = decltype(VV)::v;
    __builtin_amdgcn_s_setprio(1);
#pragma unroll
    for (int m = 0; m < 4; ++m)
#pragma unroll
      for (int n = 0; n < 4; ++n)
        acc[m][n] = __builtin_amdgcn_mfma_f32_16x16x32_bf16(alo[m], BU[n], acc[m][n], 0, 0, 0);
    __builtin_amdgcn_s_setprio(0);
#pragma unroll
    for (int m = 0; m < 4; ++m)
      ahi[m] = *(const bf16x8*)&As[c][aoff0 + 2048 + m * 512];
    if constexpr (stg) {
      __builtin_amdgcn_global_load_lds((as1cp)gA, (as3p)(As[(c + 3) & 3] + wv * 512), 16, 0, 0);
      __builtin_amdgcn_global_load_lds((as1cp)(gA + 131072), (as3p)(As[(c + 3) & 3] + 4096 + wv * 512), 16, 0, 0);
    }
    if constexpr (vm == 6) asm volatile("s_waitcnt vmcnt(6)" ::: "memory");
    else if constexpr (vm == 4) asm volatile("s_waitcnt vmcnt(4)" ::: "memory");
    else if constexpr (vm == 0) asm volatile("s_waitcnt vmcnt(0)" ::: "memory");
    asm volatile("s_barrier" ::: "memory");
    __builtin_amdgcn_s_setprio(1);
#pragma unroll
    for (int m = 0; m < 4; ++m)
#pragma unroll
      for (int n = 0; n < 4; ++n)
        acc[4 + m][n] = __builtin_amdgcn_mfma_f32_16x16x32_bf16(ahi[m], BU[n], acc[4 + m][n], 0, 0, 0);
    __builtin_amdgcn_s_setprio(0);
#pragma unroll
    for (int m = 0; m < 4; ++m)
      alo[m] = *(const bf16x8*)&As[(c + 1) & 3][aoff0 + m * 512];
#pragma unroll
    for (int n = 0; n < 4; ++n)
      BL[n] = *(const bf16x8*)&Bs[(c + 1) & 3][boff0 + n * 512];
    if constexpr (stg) {
      __builtin_amdgcn_global_load_lds((as1cp)gB, (as3p)(Bs[(c + 3) & 3] + wv * 512), 16, 0, 0);
      __builtin_amdgcn_global_load_lds((as1cp)(gB + 131072), (as3p)(Bs[(c + 3) & 3] + 4096 + wv * 512), 16, 0, 0);
      adv();
    }
    asm volatile("s_barrier" ::: "memory");
  };

  auto epi = [&](int cs2) {
    TP t = tileOf(cs2);
    float bvv[4] = {0.f, 0.f, 0.f, 0.f};
    if constexpr (HAS_BIAS) {
#pragma unroll
      for (int n = 0; n < 4; ++n) bvv[n] = p.bias[t.z][t.tn + wn + n * 16 + lrow];
    }
#pragma unroll
    for (int m = 0; m < 8; ++m)
#pragma unroll
      for (int r = 0; r < 4; ++r) {
        size_t row = (size_t)(t.tm + wm + m * 16 + lquad * 4 + r);
#pragma unroll
        for (int n = 0; n < 4; ++n) {
          int col = t.tn + wn + n * 16 + lrow;
          float vvv = acc[m][n][r] * cscale + bvv[n];
          if (OUT_BF16) ((u16*)p.C[t.z])[row * N + col] = f2bf(vvv);
          else          ((float*)p.C[t.z])[row * N + col] = vvv;
        }
      }
#pragma unroll
    for (int m2 = 0; m2 < 8; ++m2)
#pragma unroll
      for (int n2 = 0; n2 < 4; ++n2) acc[m2][n2] = (f32x4){0.f, 0.f, 0.f, 0.f};
  };

  const int total = nslot * 32;
  int cs = 0;
  for (int G = 0; G + 4 < total; G += 4) {
    kt(IC<0>{}, IC<1>{}, IC<6>{}, bg0, bg1);
    kt(IC<1>{}, IC<1>{}, IC<6>{}, bg1, bg0);
    kt(IC<2>{}, IC<1>{}, IC<6>{}, bg0, bg1);
    kt(IC<3>{}, IC<1>{}, IC<6>{}, bg1, bg0);
    if (((G + 4) & 31) == 0) { epi(cs); ++cs; }
  }
  // tail group: last stage at pos0; vmcnt tightens 6 -> 4 -> 0
  kt(IC<0>{}, IC<1>{}, IC<6>{}, bg0, bg1);
  kt(IC<1>{}, IC<0>{}, IC<4>{}, bg1, bg0);
  kt(IC<2>{}, IC<0>{}, IC<0>{}, bg0, bg1);
  kt(IC<3>{}, IC<0>{}, IC<-1>{}, bg1, bg0);
  epi(nslot - 1);
}

// ---------------------------------------------------------------------------
// gemm_pv: ctx[tile 128x256] = attn[128,K] @ vT[256,K]^T, K=(i+1)*128 causal.
// Pair (i, 31-i): every block exactly 132 K-tiles. Single-phase K-tiles:
// {MFMA | read next frags | stage g+3 | vmcnt(3) | bar}. 96 KiB LDS.
// ---------------------------------------------------------------------------
__global__ __launch_bounds__(512, 2) void gemm_pv(GemmPtrs p) {
  __shared__ __align__(16) u16 As[4][4096];   // 128 x 32
  __shared__ __align__(16) u16 Bs[4][8192];   // 256 x 32
  const int b = blockIdx.x;
  const int tid = threadIdx.x, lane = tid & 63, wv = tid >> 6;
  const int wm = (wv >> 2) << 6, wn = (wv & 3) << 6;
  const int lrow = lane & 15, lquad = lane >> 4;
  const int xs = (lquad ^ ((lrow >> 1) & 3)) << 3;
  const int aoff0 = (wm + lrow) * 32 + xs;
  const int boff0 = (wn + lrow) * 32 + xs;
  const int soff = (tid >> 2) * 4096 + (((tid & 3) ^ ((tid >> 3) & 3)) << 3);
  const int x = b & 7, u = b >> 3;
  const int P = x * 32 + u;                   // n fastest within XCD (A reuse x4)
  const int z = P >> 6, j = (P >> 2) & 15, n4 = P & 3;
  const int i1 = j, i2 = 31 - j;
  const int tn = n4 << 8;
  const int T1 = (i1 + 1) * 4;
  const int niter1 = (i2 + 1) * 4;
  const u16* Abase = p.A[z];
  const u16* Bbase = p.B[z] + (size_t)tn * 4096;

  const u16* gA = Abase + (size_t)(i1 << 7) * 4096 + soff;
  const u16* gB = Bbase + soff;
  int stk = 0, sslot = 0;
  auto adv = [&]() {
    gA += 32; gB += 32;
    ++stk;
    if (sslot == 0 && stk == T1) {
      stk = 0; sslot = 1;
      gA = Abase + (size_t)(i2 << 7) * 4096 + soff;
      gB = Bbase + soff;
    } else if (sslot == 1 && stk == niter1) {
      stk = 0; sslot = 2;
    }
  };

  f32x4 acc[4][4];
#pragma unroll
  for (int i = 0; i < 4; ++i)
#pragma unroll
    for (int jj = 0; jj < 4; ++jj) acc[i][jj] = (f32x4){0.f, 0.f, 0.f, 0.f};

  bf16x8 a0[4], a1[4], b0[4], b1[4];

  auto stage = [&](int slot) __attribute__((always_inline)) {
    __builtin_amdgcn_global_load_lds((as1cp)gA, (as3p)(As[slot] + wv * 512), 16, 0, 0);
    __builtin_amdgcn_global_load_lds((as1cp)gB, (as3p)(Bs[slot] + wv * 512), 16, 0, 0);
    __builtin_amdgcn_global_load_lds((as1cp)(gB + 524288), (as3p)(Bs[slot] + 4096 + wv * 512), 16, 0, 0);
    adv();
  };

  // prologue: tiles 0,1,2; publish 0 AND 1 (phase 0 reads tile 1)
  stage(0); stage(1); stage(2);
  asm volatile("s_waitcnt vmcnt(3)" ::: "memory");
  asm volatile("s_barrier" ::: "memory");
#pragma unroll
  for (int m = 0; m < 4; ++m) a0[m] = *(const bf16x8*)&As[0][aoff0 + m * 512];
#pragma unroll
  for (int n = 0; n < 4; ++n) b0[n] = *(const bf16x8*)&Bs[0][boff0 + n * 512];

  auto kt = [&](auto CC, auto SS, auto VV, auto& AU, auto& BU, auto& AL, auto& BL)
      __attribute__((always_inline)) {
    constexpr int c = decltype(CC)::v;
    constexpr int stg = decltype(SS)::v;
    constexpr int vm = decltype(VV)::v;
    __builtin_amdgcn_s_setprio(1);
#pragma unroll
    for (int m = 0; m < 4; ++m)
#pragma unroll
      for (int n = 0; n < 4; ++n)
        acc[m][n] = __builtin_amdgcn_mfma_f32_16x16x32_bf16(AU[m], BU[n], acc[m][n], 0, 0, 0);
    __builtin_amdgcn_s_setprio(0);
#pragma unroll
    for (int m = 0; m < 4; ++m)
      AL[m] = *(const bf16x8*)&As[(c + 1) & 3][aoff0 + m * 512];
#pragma unroll
    for (int n = 0; n < 4; ++n)
      BL[n] = *(const bf16x8*)&Bs[(c + 1) & 3][boff0 + n * 512];
    if constexpr (stg) stage((c + 3) & 3);
    if constexpr (vm == 3) asm volatile("s_waitcnt vmcnt(3)" ::: "memory");
    else if constexpr (vm == 0) asm volatile("s_waitcnt vmcnt(0)" ::: "memory");
    asm volatile("s_barrier" ::: "memory");
  };

  auto epi = [&](int s) {
    int tm = (s ? i2 : i1) << 7;
#pragma unroll
    for (int m = 0; m < 4; ++m)
#pragma unroll
      for (int r = 0; r < 4; ++r) {
        size_t row = (size_t)(tm + wm + m * 16 + lquad * 4 + r);
#pragma unroll
        for (int n = 0; n < 4; ++n) {
          int col = tn + wn + n * 16 + lrow;
          ((u16*)p.C[z])[row * 1024 + col] = f2bf(acc[m][n][r]);
        }
      }
#pragma unroll
    for (int m2 = 0; m2 < 4; ++m2)
#pragma unroll
      for (int n2 = 0; n2 < 4; ++n2) acc[m2][n2] = (f32x4){0.f, 0.f, 0.f, 0.f};
  };

  const int total = 132;
  for (int G = 0; G + 4 < total; G += 4) {
    kt(IC<0>{}, IC<1>{}, IC<3>{}, a0, b0, a1, b1);
    kt(IC<1>{}, IC<1>{}, IC<3>{}, a1, b1, a0, b0);
    kt(IC<2>{}, IC<1>{}, IC<3>{}, a0, b0, a1, b1);
    kt(IC<3>{}, IC<1>{}, IC<3>{}, a1, b1, a0, b0);
    if (G + 4 == T1) epi(0);
  }
  kt(IC<0>{}, IC<1>{}, IC<3>{}, a0, b0, a1, b1);
  kt(IC<1>{}, IC<0>{}, IC<3>{}, a1, b1, a0, b0);
  kt(IC<2>{}, IC<0>{}, IC<0>{}, a0, b0, a1, b1);
  kt(IC<3>{}, IC<0>{}, IC<-1>{}, a1, b1, a0, b0);
  epi(1);
}

// ---------------------------------------------------------------------------
extern "C" void kernel_launch(void* const* d_in, const int* in_sizes, int n_in,
                              void* d_out, int out_size, void* d_ws, size_t ws_size,
                              hipStream_t stream) {
  const float* x  = (const float*)d_in[0];
  const float* Wq = (const float*)d_in[1];
  const float* bq = (const float*)d_in[2];
  const float* Wk = (const float*)d_in[3];
  const float* bk = (const float*)d_in[4];
  const float* Wv = (const float*)d_in[5];
  const float* bv = (const float*)d_in[6];
  const float* Wo = (const float*)d_in[7];
  const float* bo = (const float*)d_in[8];

  const int S = 4096, D = 1024;
  const size_t XE = (size_t)4 * S * D;
  const size_t BSE = (size_t)S * D;

  char* ws = (char*)d_ws;
  u16* xb  = (u16*)(ws + 0);                     // [16384,1024]; dead after proj -> vT
  u16* q   = (u16*)(ws + 33554432);
  u16* k   = (u16*)(ws + 67108864);
  u16* v   = (u16*)(ws + 100663296);             // dead after transpose -> attn3
  u16* ctx = (u16*)(ws + 134217728);
  u16* wqT = (u16*)(ws + 167772160);
  u16* wkT = wqT + 1048576;
  u16* wvT = wkT + 1048576;
  u16* woT = wvT + 1048576;
  u16* attn2 = (u16*)(ws + 176160768);           // [4096,4096] bf16
  u16* attn0 = (u16*)d_out;                      // d_out 67MB, dead until out-proj
  u16* attn1 = attn0 + (size_t)S * S;
  u16* attn3 = v;
  u16* vT = xb;                                  // [1024,4096] per batch, contiguous
  u16* attn[4] = {attn0, attn1, attn2, attn3};

  // 1. cast x -> bf16
  cast_f32_bf16<<<(int)(XE / 4 / 256), 256, 0, stream>>>(x, xb, (int)(XE / 4));
  // 2. weight transposes
  {
    TransPtrs tp = {{Wq, Wk, Wv, Wo}, {wqT, wkT, wvT, woT}};
    transpose_to_bf16<true><<<dim3(32, 32, 4), dim3(32, 8), 0, stream>>>(tp, D, D);
  }
  // 3. q/k/v projections: 768 tiles = 256 blocks x 3 slots (z = slot)
  {
    GemmPtrs gp = {{xb, xb, xb, xb}, {wqT, wkT, wvT, wqT},
                   {bq, bk, bv, bq}, {q, k, v, q}};
    gemm256p<0, true, true><<<256, 512, 0, stream>>>(gp, D, 1.0f);
  }
  // 4. v -> v^T per batch (overwrites dead xb)
  {
    TransPtrs tp = {{v, v + BSE, v + 2 * BSE, v + 3 * BSE},
                    {vT, vT + BSE, vT + 2 * BSE, vT + 3 * BSE}};
    transpose_to_bf16<false><<<dim3(D / 32, S / 32, 4), dim3(32, 8), 0, stream>>>(tp, S, D);
  }
  // 5. scores = (q k^T)*scale: 544 tri tiles, per-XCD contiguous 68-ranges
  {
    GemmPtrs gp = {{q, q + BSE, q + 2 * BSE, q + 3 * BSE},
                   {k, k + BSE, k + 2 * BSE, k + 3 * BSE},
                   {nullptr, nullptr, nullptr, nullptr},
                   {attn[0], attn[1], attn[2], attn[3]}};
    gemm256p<1, true, false><<<256, 512, 0, stream>>>(gp, S, 0.03125f);
  }
  // 6. causal softmax in-place (trimmed + fringe zeros)
  {
    SmPtrs sp = {{attn[0], attn[1], attn[2], attn[3]}};
    softmax_causal<<<dim3(S, 4), 256, 0, stream>>>(sp);
  }
  // 7. ctx = attn @ v: paired causal tiles, 256 blocks x 132 K-tiles (balanced)
  {
    GemmPtrs gp = {{attn[0], attn[1], attn[2], attn[3]},
                   {vT, vT + BSE, vT + 2 * BSE, vT + 3 * BSE},
                   {nullptr, nullptr, nullptr, nullptr},
                   {ctx, ctx + BSE, ctx + 2 * BSE, ctx + 3 * BSE}};
    gemm_pv<<<256, 512, 0, stream>>>(gp);
  }
  // 8. out = ctx Wo^T + bo (fp32 -> d_out)
  {
    GemmPtrs gp = {{ctx, ctx, ctx, ctx}, {woT, woT, woT, woT},
                   {bo, bo, bo, bo}, {d_out, d_out, d_out, d_out}};
    gemm256p<3, false, true><<<256, 512, 0, stream>>>(gp, D, 1.0f);
  }
}

// Round 3
// 508.856 us; speedup vs baseline: 1.0291x; 1.0266x over previous
//
#include <hip/hip_runtime.h>

// ---------------------------------------------------------------------------
// StandAttention: out = softmax_causal((xWq+bq)(xWk+bk)^T / sqrt(d)) (xWv+bv) Wo + bo
// b=4, s=4096, d=1024. fp32 in/out, bf16 MFMA compute.
//
// R9 changes vs R8 (R8: 522 us; MfmaUtil pinned at 37% across THREE macro-
// schedules -> diagnosis: in-order issue serializes matrix pipe and LDS pipe.
// A wave's 16 back-to-back MFMAs occupy its issue stream for the whole
// matrix-pipe window (~620cy/SIMD), so ds_reads only enter the LDS pipe
// afterwards; all waves are barrier-locked to the same phase, so the two
// pipes strictly alternate: 620+130+620+640+sync ~= 2900cy/K-tile measured):
//  - sched_group_barrier pipelines (CK v3 / T19 pattern) in every phase:
//    {MFMA x2, DS_READ x1} x(4|8) + VMEM x2 -> ds_reads issue every 2 MFMAs,
//    LDS pipe runs concurrently with matrix pipe. setprio bracket widened to
//    cover the interleaved body (setprio may bound scheduling regions).
//  - no other changes vs R8 (clean attribution).
// ---------------------------------------------------------------------------

typedef unsigned short u16;
typedef __attribute__((ext_vector_type(4))) unsigned short u16x4;
typedef __attribute__((ext_vector_type(8))) unsigned short u16x8;
typedef __attribute__((ext_vector_type(8))) __bf16 bf16x8;
typedef __attribute__((ext_vector_type(4))) float f32x4;

typedef const __attribute__((address_space(1))) void* as1cp;
typedef __attribute__((address_space(3))) void* as3p;

template <int N> struct IC { static constexpr int v = N; };

#define SGB(mask, n) __builtin_amdgcn_sched_group_barrier((mask), (n), 0)
// masks: MFMA=0x8, VMEM=0x10, DS_READ=0x100

struct GemmPtrs {
  const u16* A[4];
  const u16* B[4];
  const float* bias[4];
  void* C[4];
};
struct TransPtrs {
  const void* in[4];
  u16* out[4];
};
struct SmPtrs {
  u16* P[4];
};

__device__ __forceinline__ u16 f2bf(float f) {
  union { float f; unsigned int i; } c; c.f = f;
  unsigned int r = c.i + 0x7fffu + ((c.i >> 16) & 1u);   // RNE
  return (u16)(r >> 16);
}
__device__ __forceinline__ float bf2f(u16 u) {
  union { unsigned int i; float f; } c; c.i = ((unsigned int)u) << 16;
  return c.f;
}

// ---------------- cast fp32 -> bf16 (vectorized) ----------------
__global__ __launch_bounds__(256) void cast_f32_bf16(const float* __restrict__ in,
                                                     u16* __restrict__ out, int n4) {
  int i = blockIdx.x * blockDim.x + threadIdx.x;
  if (i >= n4) return;
  float4 v = ((const float4*)in)[i];
  u16x4 u;
  u.x = f2bf(v.x); u.y = f2bf(v.y); u.z = f2bf(v.z); u.w = f2bf(v.w);
  ((u16x4*)out)[i] = u;
}

// ---------------- LDS-tiled transpose (-> bf16), batched by z ----------------
template <bool IN_F32>
__global__ __launch_bounds__(256) void transpose_to_bf16(TransPtrs tp, int R, int C) {
  __shared__ u16 t[32][34];
  int z = blockIdx.z;
  int tx = threadIdx.x, ty = threadIdx.y;
  int c0 = blockIdx.x * 32, r0 = blockIdx.y * 32;
#pragma unroll
  for (int dy = 0; dy < 4; ++dy) {
    int r = r0 + ty + dy * 8;
    int c = c0 + tx;
    u16 hv;
    if (IN_F32) hv = f2bf(((const float*)tp.in[z])[(size_t)r * C + c]);
    else        hv = ((const u16*)tp.in[z])[(size_t)r * C + c];
    t[ty + dy * 8][tx] = hv;
  }
  __syncthreads();
  u16* op = tp.out[z];
#pragma unroll
  for (int dy = 0; dy < 4; ++dy) {
    int a = ty + dy * 8;
    op[(size_t)(c0 + a) * R + r0 + tx] = t[tx][a];
  }
}

// ---------------- causal softmax, in-place, trimmed to j<=row ----------------
__global__ __launch_bounds__(256) void softmax_causal(SmPtrs sp) {
  int row = blockIdx.x;
  u16* P = sp.P[blockIdx.y];
  int tid = threadIdx.x;
  int lane = tid & 63, wv = tid >> 6;
  u16x8* prow = (u16x8*)(P + (size_t)row * 4096);
  int nch = (row >> 3) + 1;           // vec8 chunks containing any j<=row
  int fend = ((row >> 7) + 1) << 4;   // chunks to the 128 boundary PV reads
  int c0 = tid, c1 = tid + 256;
  bool a0 = c0 < nch, a1 = c1 < nch;
  float vals[16];
  float lmax = -3.0e38f;
  if (a0) {
    u16x8 u = prow[c0];
#pragma unroll
    for (int e = 0; e < 8; ++e) {
      float f = (c0 * 8 + e <= row) ? bf2f(u[e]) : -3.0e38f;
      vals[e] = f; lmax = fmaxf(lmax, f);
    }
  } else {
#pragma unroll
    for (int e = 0; e < 8; ++e) vals[e] = -3.0e38f;
  }
  if (a1) {
    u16x8 u = prow[c1];
#pragma unroll
    for (int e = 0; e < 8; ++e) {
      float f = (c1 * 8 + e <= row) ? bf2f(u[e]) : -3.0e38f;
      vals[8 + e] = f; lmax = fmaxf(lmax, f);
    }
  } else {
#pragma unroll
    for (int e = 0; e < 8; ++e) vals[8 + e] = -3.0e38f;
  }
  __shared__ float red[8];
#pragma unroll
  for (int off = 32; off > 0; off >>= 1) lmax = fmaxf(lmax, __shfl_down(lmax, off, 64));
  if (lane == 0) red[wv] = lmax;
  __syncthreads();
  float m2 = fmaxf(fmaxf(red[0], red[1]), fmaxf(red[2], red[3]));
  float lsum = 0.f;
#pragma unroll
  for (int e = 0; e < 16; ++e) {
    float ev = __expf(vals[e] - m2);
    vals[e] = ev;
    lsum += ev;
  }
#pragma unroll
  for (int off = 32; off > 0; off >>= 1) lsum += __shfl_down(lsum, off, 64);
  if (lane == 0) red[4 + wv] = lsum;
  __syncthreads();
  float inv = 1.0f / (red[4] + red[5] + red[6] + red[7]);
  if (a0) {
    u16x8 u;
#pragma unroll
    for (int e = 0; e < 8; ++e) u[e] = f2bf(vals[e] * inv);
    prow[c0] = u;
  }
  if (a1) {
    u16x8 u;
#pragma unroll
    for (int e = 0; e < 8; ++e) u[e] = f2bf(vals[8 + e] * inv);
    prow[c1] = u;
  }
  u16x8 zz = (u16x8)(u16)0;
  for (int c = nch + tid; c < fend; c += 256) prow[c] = zz;
}

// ---------------------------------------------------------------------------
// gemm256p: 256x256-tile register-pipelined GEMM. C = A[M,1024] @ Bt[N,1024]^T
// 8 waves (2M x 4N), per-wave 128x64 out. BK=32, 4-slot LDS ring, stage
// distance 3, one barrier per phase, vmcnt(6) once per K-tile, SGB interleave.
// MODE 0: q/k/v proj (3 slots, z=slot)  MODE 1: causal scores (3|2 slots)
// MODE 3: out-projection (1 slot)
// ---------------------------------------------------------------------------
template <int MODE, bool OUT_BF16, bool HAS_BIAS>
__global__ __launch_bounds__(512, 2) void gemm256p(GemmPtrs p, int N, float cscale) {
  __shared__ __align__(16) u16 As[4][8192];   // 4 slots x 256 rows x 32 k
  __shared__ __align__(16) u16 Bs[4][8192];
  const int b = blockIdx.x;
  const int tid = threadIdx.x, lane = tid & 63, wv = tid >> 6;
  const int wm = (wv >> 2) << 7, wn = (wv & 3) << 6;
  const int lrow = lane & 15, lquad = lane >> 4;
  const int xs = (lquad ^ ((lrow >> 1) & 3)) << 3;
  const int aoff0 = (wm + lrow) * 32 + xs;
  const int boff0 = (wn + lrow) * 32 + xs;
  // stage src pre-swizzle: LDS[r][c] = G[r][c ^ ((r>>1)&3)]
  const int soff = (tid >> 2) * 1024 + (((tid & 3) ^ ((tid >> 3) & 3)) << 3);
  const int x = b & 7, u = b >> 3;            // XCD, index-on-XCD
  const int nslot = (MODE == 1) ? (u < 4 ? 3 : 2) : (MODE == 0 ? 3 : 1);

  struct TP { const u16* A; const u16* B; int tm, tn, z; };
  auto tileOf = [&](int s) {
    TP t;
    if (MODE == 0) {
      int i = x * 32 + u;                 // 8-row band per XCD, reused over 3 mats
      t.z = s; t.tm = (i >> 2) << 8; t.tn = (i & 3) << 8;
    } else if (MODE == 1) {
      int g = x * 68 + s * 32 + u;        // per-XCD contiguous tri range
      t.z = g / 136; int L = g - t.z * 136;
      int i = (int)((__fsqrt_rn(8.f * (float)L + 1.f) - 1.f) * 0.5f);
      while ((i + 1) * (i + 2) / 2 <= L) ++i;
      while (i * (i + 1) / 2 > L) --i;
      t.tm = i << 8; t.tn = (L - ((i * (i + 1)) >> 1)) << 8;
    } else {
      int i = x * 32 + u;
      t.z = 0; t.tm = (i >> 2) << 8; t.tn = (i & 3) << 8;
    }
    t.A = p.A[t.z] + (size_t)t.tm * 1024;
    t.B = p.B[t.z] + (size_t)t.tn * 1024;
    return t;
  };

  // staging cursor (3 K-tiles ahead of compute)
  const u16* gA; const u16* gB; int stk = 0, sslot = 0;
  {
    TP t0 = tileOf(0);
    gA = t0.A + soff; gB = t0.B + soff;
  }
  auto adv = [&]() {
    gA += 32; gB += 32;
    ++stk;
    if (stk == 32 && sslot < nslot) {
      stk = 0; ++sslot;
      if (sslot < nslot) {
        TP t = tileOf(sslot);
        gA = t.A + soff; gB = t.B + soff;
      }
    }
  };

  f32x4 acc[8][4];
#pragma unroll
  for (int i = 0; i < 8; ++i)
#pragma unroll
    for (int j = 0; j < 4; ++j) acc[i][j] = (f32x4){0.f, 0.f, 0.f, 0.f};

  bf16x8 alo[4], ahi[4], bg0[4], bg1[4];

  // prologue: stage tiles 0,1,2 -> slots 0,1,2; publish tile 0; preload (0,0)
#pragma unroll
  for (int pt = 0; pt < 3; ++pt) {
    __builtin_amdgcn_global_load_lds((as1cp)gA, (as3p)(As[pt] + wv * 512), 16, 0, 0);
    __builtin_amdgcn_global_load_lds((as1cp)(gA + 131072), (as3p)(As[pt] + 4096 + wv * 512), 16, 0, 0);
    __builtin_amdgcn_global_load_lds((as1cp)gB, (as3p)(Bs[pt] + wv * 512), 16, 0, 0);
    __builtin_amdgcn_global_load_lds((as1cp)(gB + 131072), (as3p)(Bs[pt] + 4096 + wv * 512), 16, 0, 0);
    adv();
  }
  asm volatile("s_waitcnt vmcnt(8)" ::: "memory");
  asm volatile("s_barrier" ::: "memory");
#pragma unroll
  for (int m = 0; m < 4; ++m) alo[m] = *(const bf16x8*)&As[0][aoff0 + m * 512];
#pragma unroll
  for (int n = 0; n < 4; ++n) bg0[n] = *(const bf16x8*)&Bs[0][boff0 + n * 512];

  // one K-tile: ph0 {MFMA lo <interleaved> read ahi + stageA(g+3) | vmcnt(6) | bar}
  //             ph1 {MFMA hi <interleaved> read next alo+B + stageB(g+3) | bar}
  auto kt = [&](auto CC, auto SS, auto VV, auto& BU, auto& BL)
      __attribute__((always_inline)) {
    constexpr int c = decltype(CC)::v;
    constexpr int stg = decltype(SS)::v;
    constexpr int vm = decltype(VV)::v;
    __builtin_amdgcn_s_setprio(1);
#pragma unroll
    for (int m = 0; m < 4; ++m)
#pragma unroll
      for (int n = 0; n < 4; ++n)
        acc[m][n] = __builtin_amdgcn_mfma_f32_16x16x32_bf16(alo[m], BU[n], acc[m][n], 0, 0, 0);
#pragma unroll
    for (int m = 0; m < 4; ++m)
      ahi[m] = *(const bf16x8*)&As[c][aoff0 + 2048 + m * 512];
    if constexpr (stg) {
      __builtin_amdgcn_global_load_lds((as1cp)gA, (as3p)(As[(c + 3) & 3] + wv * 512), 16, 0, 0);
      __builtin_amdgcn_global_load_lds((as1cp)(gA + 131072), (as3p)(As[(c + 3) & 3] + 4096 + wv * 512), 16, 0, 0);
    }
    // pipeline: a ds_read every 2 MFMAs; stage loads mid-cluster
    SGB(0x8, 2); SGB(0x100, 1);
    SGB(0x8, 2); SGB(0x100, 1);
    SGB(0x8, 2); SGB(0x100, 1);
    SGB(0x8, 2); SGB(0x100, 1);
    SGB(0x8, 4); SGB(0x10, 2);
    SGB(0x8, 4);
    __builtin_amdgcn_s_setprio(0);
    if constexpr (vm == 6) asm volatile("s_waitcnt vmcnt(6)" ::: "memory");
    else if constexpr (vm == 4) asm volatile("s_waitcnt vmcnt(4)" ::: "memory");
    else if constexpr (vm == 0) asm volatile("s_waitcnt vmcnt(0)" ::: "memory");
    asm volatile("s_barrier" ::: "memory");
    __builtin_amdgcn_s_setprio(1);
#pragma unroll
    for (int m = 0; m < 4; ++m)
#pragma unroll
      for (int n = 0; n < 4; ++n)
        acc[4 + m][n] = __builtin_amdgcn_mfma_f32_16x16x32_bf16(ahi[m], BU[n], acc[4 + m][n], 0, 0, 0);
#pragma unroll
    for (int m = 0; m < 4; ++m)
      alo[m] = *(const bf16x8*)&As[(c + 1) & 3][aoff0 + m * 512];
#pragma unroll
    for (int n = 0; n < 4; ++n)
      BL[n] = *(const bf16x8*)&Bs[(c + 1) & 3][boff0 + n * 512];
    if constexpr (stg) {
      __builtin_amdgcn_global_load_lds((as1cp)gB, (as3p)(Bs[(c + 3) & 3] + wv * 512), 16, 0, 0);
      __builtin_amdgcn_global_load_lds((as1cp)(gB + 131072), (as3p)(Bs[(c + 3) & 3] + 4096 + wv * 512), 16, 0, 0);
      adv();
    }
    SGB(0x8, 2); SGB(0x100, 1);
    SGB(0x8, 2); SGB(0x100, 1);
    SGB(0x8, 2); SGB(0x100, 1);
    SGB(0x8, 2); SGB(0x100, 1);
    SGB(0x8, 2); SGB(0x100, 1);
    SGB(0x8, 2); SGB(0x100, 1);
    SGB(0x8, 2); SGB(0x100, 1);
    SGB(0x8, 2); SGB(0x100, 1);
    SGB(0x10, 2);
    __builtin_amdgcn_s_setprio(0);
    asm volatile("s_barrier" ::: "memory");
  };

  auto epi = [&](int cs2) {
    TP t = tileOf(cs2);
    float bvv[4] = {0.f, 0.f, 0.f, 0.f};
    if constexpr (HAS_BIAS) {
#pragma unroll
      for (int n = 0; n < 4; ++n) bvv[n] = p.bias[t.z][t.tn + wn + n * 16 + lrow];
    }
#pragma unroll
    for (int m = 0; m < 8; ++m)
#pragma unroll
      for (int r = 0; r < 4; ++r) {
        size_t row = (size_t)(t.tm + wm + m * 16 + lquad * 4 + r);
#pragma unroll
        for (int n = 0; n < 4; ++n) {
          int col = t.tn + wn + n * 16 + lrow;
          float vvv = acc[m][n][r] * cscale + bvv[n];
          if (OUT_BF16) ((u16*)p.C[t.z])[row * N + col] = f2bf(vvv);
          else          ((float*)p.C[t.z])[row * N + col] = vvv;
        }
      }
#pragma unroll
    for (int m2 = 0; m2 < 8; ++m2)
#pragma unroll
      for (int n2 = 0; n2 < 4; ++n2) acc[m2][n2] = (f32x4){0.f, 0.f, 0.f, 0.f};
  };

  const int total = nslot * 32;
  int cs = 0;
  for (int G = 0; G + 4 < total; G += 4) {
    kt(IC<0>{}, IC<1>{}, IC<6>{}, bg0, bg1);
    kt(IC<1>{}, IC<1>{}, IC<6>{}, bg1, bg0);
    kt(IC<2>{}, IC<1>{}, IC<6>{}, bg0, bg1);
    kt(IC<3>{}, IC<1>{}, IC<6>{}, bg1, bg0);
    if (((G + 4) & 31) == 0) { epi(cs); ++cs; }
  }
  // tail group: last stage at pos0; vmcnt tightens 6 -> 4 -> 0
  kt(IC<0>{}, IC<1>{}, IC<6>{}, bg0, bg1);
  kt(IC<1>{}, IC<0>{}, IC<4>{}, bg1, bg0);
  kt(IC<2>{}, IC<0>{}, IC<0>{}, bg0, bg1);
  kt(IC<3>{}, IC<0>{}, IC<-1>{}, bg1, bg0);
  epi(nslot - 1);
}

// ---------------------------------------------------------------------------
// gemm_pv: ctx[tile 128x256] = attn[128,K] @ vT[256,K]^T, K=(i+1)*128 causal.
// Pair (i, 31-i): every block exactly 132 K-tiles. Single-phase K-tiles:
// {MFMA <interleaved> read next frags + stage g+3 | vmcnt(3) | bar}. 96 KiB LDS.
// ---------------------------------------------------------------------------
__global__ __launch_bounds__(512, 2) void gemm_pv(GemmPtrs p) {
  __shared__ __align__(16) u16 As[4][4096];   // 128 x 32
  __shared__ __align__(16) u16 Bs[4][8192];   // 256 x 32
  const int b = blockIdx.x;
  const int tid = threadIdx.x, lane = tid & 63, wv = tid >> 6;
  const int wm = (wv >> 2) << 6, wn = (wv & 3) << 6;
  const int lrow = lane & 15, lquad = lane >> 4;
  const int xs = (lquad ^ ((lrow >> 1) & 3)) << 3;
  const int aoff0 = (wm + lrow) * 32 + xs;
  const int boff0 = (wn + lrow) * 32 + xs;
  const int soff = (tid >> 2) * 4096 + (((tid & 3) ^ ((tid >> 3) & 3)) << 3);
  const int x = b & 7, u = b >> 3;
  const int P = x * 32 + u;                   // n fastest within XCD (A reuse x4)
  const int z = P >> 6, j = (P >> 2) & 15, n4 = P & 3;
  const int i1 = j, i2 = 31 - j;
  const int tn = n4 << 8;
  const int T1 = (i1 + 1) * 4;
  const int niter1 = (i2 + 1) * 4;
  const u16* Abase = p.A[z];
  const u16* Bbase = p.B[z] + (size_t)tn * 4096;

  const u16* gA = Abase + (size_t)(i1 << 7) * 4096 + soff;
  const u16* gB = Bbase + soff;
  int stk = 0, sslot = 0;
  auto adv = [&]() {
    gA += 32; gB += 32;
    ++stk;
    if (sslot == 0 && stk == T1) {
      stk = 0; sslot = 1;
      gA = Abase + (size_t)(i2 << 7) * 4096 + soff;
      gB = Bbase + soff;
    } else if (sslot == 1 && stk == niter1) {
      stk = 0; sslot = 2;
    }
  };

  f32x4 acc[4][4];
#pragma unroll
  for (int i = 0; i < 4; ++i)
#pragma unroll
    for (int jj = 0; jj < 4; ++jj) acc[i][jj] = (f32x4){0.f, 0.f, 0.f, 0.f};

  bf16x8 a0[4], a1[4], b0[4], b1[4];

  auto stage = [&](int slot) __attribute__((always_inline)) {
    __builtin_amdgcn_global_load_lds((as1cp)gA, (as3p)(As[slot] + wv * 512), 16, 0, 0);
    __builtin_amdgcn_global_load_lds((as1cp)gB, (as3p)(Bs[slot] + wv * 512), 16, 0, 0);
    __builtin_amdgcn_global_load_lds((as1cp)(gB + 524288), (as3p)(Bs[slot] + 4096 + wv * 512), 16, 0, 0);
    adv();
  };

  // prologue: tiles 0,1,2; publish 0 AND 1 (phase 0 reads tile 1)
  stage(0); stage(1); stage(2);
  asm volatile("s_waitcnt vmcnt(3)" ::: "memory");
  asm volatile("s_barrier" ::: "memory");
#pragma unroll
  for (int m = 0; m < 4; ++m) a0[m] = *(const bf16x8*)&As[0][aoff0 + m * 512];
#pragma unroll
  for (int n = 0; n < 4; ++n) b0[n] = *(const bf16x8*)&Bs[0][boff0 + n * 512];

  auto kt = [&](auto CC, auto SS, auto VV, auto& AU, auto& BU, auto& AL, auto& BL)
      __attribute__((always_inline)) {
    constexpr int c = decltype(CC)::v;
    constexpr int stg = decltype(SS)::v;
    constexpr int vm = decltype(VV)::v;
    __builtin_amdgcn_s_setprio(1);
#pragma unroll
    for (int m = 0; m < 4; ++m)
#pragma unroll
      for (int n = 0; n < 4; ++n)
        acc[m][n] = __builtin_amdgcn_mfma_f32_16x16x32_bf16(AU[m], BU[n], acc[m][n], 0, 0, 0);
#pragma unroll
    for (int m = 0; m < 4; ++m)
      AL[m] = *(const bf16x8*)&As[(c + 1) & 3][aoff0 + m * 512];
#pragma unroll
    for (int n = 0; n < 4; ++n)
      BL[n] = *(const bf16x8*)&Bs[(c + 1) & 3][boff0 + n * 512];
    if constexpr (stg) stage((c + 3) & 3);
    SGB(0x8, 2); SGB(0x100, 1);
    SGB(0x8, 2); SGB(0x100, 1);
    SGB(0x8, 2); SGB(0x100, 1);
    SGB(0x8, 2); SGB(0x100, 1);
    SGB(0x8, 2); SGB(0x100, 1);
    SGB(0x8, 2); SGB(0x100, 1);
    SGB(0x8, 2); SGB(0x100, 1);
    SGB(0x8, 2); SGB(0x100, 1);
    SGB(0x10, 3);
    __builtin_amdgcn_s_setprio(0);
    if constexpr (vm == 3) asm volatile("s_waitcnt vmcnt(3)" ::: "memory");
    else if constexpr (vm == 0) asm volatile("s_waitcnt vmcnt(0)" ::: "memory");
    asm volatile("s_barrier" ::: "memory");
  };

  auto epi = [&](int s) {
    int tm = (s ? i2 : i1) << 7;
#pragma unroll
    for (int m = 0; m < 4; ++m)
#pragma unroll
      for (int r = 0; r < 4; ++r) {
        size_t row = (size_t)(tm + wm + m * 16 + lquad * 4 + r);
#pragma unroll
        for (int n = 0; n < 4; ++n) {
          int col = tn + wn + n * 16 + lrow;
          ((u16*)p.C[z])[row * 1024 + col] = f2bf(acc[m][n][r]);
        }
      }
#pragma unroll
    for (int m2 = 0; m2 < 4; ++m2)
#pragma unroll
      for (int n2 = 0; n2 < 4; ++n2) acc[m2][n2] = (f32x4){0.f, 0.f, 0.f, 0.f};
  };

  const int total = 132;
  for (int G = 0; G + 4 < total; G += 4) {
    kt(IC<0>{}, IC<1>{}, IC<3>{}, a0, b0, a1, b1);
    kt(IC<1>{}, IC<1>{}, IC<3>{}, a1, b1, a0, b0);
    kt(IC<2>{}, IC<1>{}, IC<3>{}, a0, b0, a1, b1);
    kt(IC<3>{}, IC<1>{}, IC<3>{}, a1, b1, a0, b0);
    if (G + 4 == T1) epi(0);
  }
  kt(IC<0>{}, IC<1>{}, IC<3>{}, a0, b0, a1, b1);
  kt(IC<1>{}, IC<0>{}, IC<3>{}, a1, b1, a0, b0);
  kt(IC<2>{}, IC<0>{}, IC<0>{}, a0, b0, a1, b1);
  kt(IC<3>{}, IC<0>{}, IC<-1>{}, a1, b1, a0, b0);
  epi(1);
}

// ---------------------------------------------------------------------------
extern "C" void kernel_launch(void* const* d_in, const int* in_sizes, int n_in,
                              void* d_out, int out_size, void* d_ws, size_t ws_size,
                              hipStream_t stream) {
  const float* x  = (const float*)d_in[0];
  const float* Wq = (const float*)d_in[1];
  const float* bq = (const float*)d_in[2];
  const float* Wk = (const float*)d_in[3];
  const float* bk = (const float*)d_in[4];
  const float* Wv = (const float*)d_in[5];
  const float* bv = (const float*)d_in[6];
  const float* Wo = (const float*)d_in[7];
  const float* bo = (const float*)d_in[8];

  const int S = 4096, D = 1024;
  const size_t XE = (size_t)4 * S * D;
  const size_t BSE = (size_t)S * D;

  char* ws = (char*)d_ws;
  u16* xb  = (u16*)(ws + 0);                     // [16384,1024]; dead after proj -> vT
  u16* q   = (u16*)(ws + 33554432);
  u16* k   = (u16*)(ws + 67108864);
  u16* v   = (u16*)(ws + 100663296);             // dead after transpose -> attn3
  u16* ctx = (u16*)(ws + 134217728);
  u16* wqT = (u16*)(ws + 167772160);
  u16* wkT = wqT + 1048576;
  u16* wvT = wkT + 1048576;
  u16* woT = wvT + 1048576;
  u16* attn2 = (u16*)(ws + 176160768);           // [4096,4096] bf16
  u16* attn0 = (u16*)d_out;                      // d_out 67MB, dead until out-proj
  u16* attn1 = attn0 + (size_t)S * S;
  u16* attn3 = v;
  u16* vT = xb;                                  // [1024,4096] per batch, contiguous
  u16* attn[4] = {attn0, attn1, attn2, attn3};

  // 1. cast x -> bf16
  cast_f32_bf16<<<(int)(XE / 4 / 256), 256, 0, stream>>>(x, xb, (int)(XE / 4));
  // 2. weight transposes
  {
    TransPtrs tp = {{Wq, Wk, Wv, Wo}, {wqT, wkT, wvT, woT}};
    transpose_to_bf16<true><<<dim3(32, 32, 4), dim3(32, 8), 0, stream>>>(tp, D, D);
  }
  // 3. q/k/v projections: 768 tiles = 256 blocks x 3 slots (z = slot)
  {
    GemmPtrs gp = {{xb, xb, xb, xb}, {wqT, wkT, wvT, wqT},
                   {bq, bk, bv, bq}, {q, k, v, q}};
    gemm256p<0, true, true><<<256, 512, 0, stream>>>(gp, D, 1.0f);
  }
  // 4. v -> v^T per batch (overwrites dead xb)
  {
    TransPtrs tp = {{v, v + BSE, v + 2 * BSE, v + 3 * BSE},
                    {vT, vT + BSE, vT + 2 * BSE, vT + 3 * BSE}};
    transpose_to_bf16<false><<<dim3(D / 32, S / 32, 4), dim3(32, 8), 0, stream>>>(tp, S, D);
  }
  // 5. scores = (q k^T)*scale: 544 tri tiles, per-XCD contiguous 68-ranges
  {
    GemmPtrs gp = {{q, q + BSE, q + 2 * BSE, q + 3 * BSE},
                   {k, k + BSE, k + 2 * BSE, k + 3 * BSE},
                   {nullptr, nullptr, nullptr, nullptr},
                   {attn[0], attn[1], attn[2], attn[3]}};
    gemm256p<1, true, false><<<256, 512, 0, stream>>>(gp, S, 0.03125f);
  }
  // 6. causal softmax in-place (trimmed + fringe zeros)
  {
    SmPtrs sp = {{attn[0], attn[1], attn[2], attn[3]}};
    softmax_causal<<<dim3(S, 4), 256, 0, stream>>>(sp);
  }
  // 7. ctx = attn @ v: paired causal tiles, 256 blocks x 132 K-tiles (balanced)
  {
    GemmPtrs gp = {{attn[0], attn[1], attn[2], attn[3]},
                   {vT, vT + BSE, vT + 2 * BSE, vT + 3 * BSE},
                   {nullptr, nullptr, nullptr, nullptr},
                   {ctx, ctx + BSE, ctx + 2 * BSE, ctx + 3 * BSE}};
    gemm_pv<<<256, 512, 0, stream>>>(gp);
  }
  // 8. out = ctx Wo^T + bo (fp32 -> d_out)
  {
    GemmPtrs gp = {{ctx, ctx, ctx, ctx}, {woT, woT, woT, woT},
                   {bo, bo, bo, bo}, {d_out, d_out, d_out, d_out}};
    gemm256p<3, false, true><<<256, 512, 0, stream>>>(gp, D, 1.0f);
  }
}